// Round 5
// baseline (734.838 us; speedup 1.0000x reference)
//
#include <hip/hip_runtime.h>

// Problem constants
#define T_STEPS 100
#define BATCH   512
#define D0      700
#define D1      512
#define D2      20
#define M_ROWS  (T_STEPS * BATCH)   // 51200

// Output layout (floats): [s2 (T*B*20) | s1 (T*B*512) | s2 copy (T*B*20)]
#define OFF_S2A 0
#define OFF_S1  (T_STEPS * BATCH * D2)                    // 1,024,000
#define OFF_S2B (OFF_S1 + T_STEPS * BATCH * D1)           // 27,238,400

__device__ __constant__ const float kALPHA = 0.8f;
__device__ __constant__ const float kBETA  = 0.9f;
__device__ __constant__ const float kTHR   = 1.0f;

// ---------------------------------------------------------------------------
// GEMM1: C[M,512] = A[M,700] * W1[512,700]^T   (both row-major, K contiguous)
// 128x128 tile, BK=32, **128 threads, 16x8 microtile** (16 ty-groups? no:
// ty=tid>>4 in 0..7 owns 16 rows; tx=tid&15 owns 8 cols).
// Rationale: 8x8 microtile = 2 FLOP per LDS byte -> LDS return BW (~85-112
// B/cy/CU) needs ~1.25-1.5x the FMA time -> port-bound (VALUBusy stuck ~54%).
// 16x8 = 2.67 FLOP/B -> port/FMA ~0.9. Same k-summation order => bitwise-
// identical C. 32KB LDS, 2-wave blocks, 4 blocks/CU (8 waves, phase-diverse).
//
// Grid swizzle (T1, kept from R4 — FETCH 287->102MB): 1-D grid of 1600; XCD
// x (= id%8) owns row-panels [50x,50x+50), col fastest within XCD.
//
// LDS tiles stored [BK][BM] with a 16B-chunk XOR swizzle:
//   element m of k-row k lives at chunk  (m>>2) ^ (((m>>2)>>3)&3) ^ ((k>>2)&7)
//   - staging writes (transposed b32 scatter)  2 lanes/bank  (free)
//   - B-fragment float4 reads                  2 addrs/slot  (256B minimum)
//   - A-fragment float4 reads (4ty+d chunks)   4 distinct bank-quads (free)
// ---------------------------------------------------------------------------
constexpr int BM = 128, BN = 128, BK = 32;

// swizzled float index of element m in k-row k (tile row stride = 128 floats)
__device__ __forceinline__ int swz(int k, int m) {
    const int c = m >> 2;
    const int cpos = c ^ ((c >> 3) & 3) ^ ((k >> 2) & 7);
    return k * BM + (cpos << 2) + (m & 3);
}

__global__ __launch_bounds__(128)
void gemm1_kernel(const float* __restrict__ A, const float* __restrict__ W,
                  float* __restrict__ C) {
    __shared__ float As[BK * BM];
    __shared__ float Ws[BK * BN];

    // XCD-chunked remap: 1600 blocks, 8 XCDs, 200 blocks each.
    const int d     = blockIdx.x;
    const int xcd   = d & 7;
    const int local = d >> 3;            // 0..199
    const int brow  = xcd * 50 + (local >> 2);
    const int bcol  = local & 3;

    const int tid  = threadIdx.x;        // 0..127
    const int row0 = brow * BM;
    const int col0 = bcol * BN;

    const int tx = tid & 15;             // 16 cols of threads (8 N each)
    const int ty = tid >> 4;             // 8 row-groups (16 M each)

    // swizzle chunk bases (k-part XORed in inner loop)
    int ca[4];
#pragma unroll
    for (int dd = 0; dd < 4; ++dd) {
        const int u = 4 * ty + dd;
        ca[dd] = u ^ ((u >> 3) & 3);
    }
    const int cb0 = (2 * tx)     ^ (((2 * tx)     >> 3) & 3);
    const int cb1 = (2 * tx + 1) ^ (((2 * tx + 1) >> 3) & 3);

    float acc[16][8];
#pragma unroll
    for (int i = 0; i < 16; ++i)
#pragma unroll
        for (int j = 0; j < 8; ++j) acc[i][j] = 0.f;

    const int NT = (D0 + BK - 1) / BK;  // 22 (last tile zero-padded)
    for (int kt = 0; kt < NT; ++kt) {
        const int k0 = kt * BK;
        // Stage A-tile and W-tile: each 128 rows x 32 k = 1024 float4;
        // 8 float4 per thread per tile per array.
        float4 va[8], vw[8];
#pragma unroll
        for (int l = 0; l < 8; ++l) {
            const int f  = tid + l * 128;   // 0..1023
            const int r  = f >> 3;          // 8 float4 per row
            const int k  = (f & 7) * 4;
            const int gk = k0 + k;
            if (gk + 3 < D0) {
                va[l] = *(const float4*)(A + (size_t)(row0 + r) * D0 + gk);
                vw[l] = *(const float4*)(W + (size_t)(col0 + r) * D0 + gk);
            } else {
                const float* ap = A + (size_t)(row0 + r) * D0;
                const float* wp = W + (size_t)(col0 + r) * D0;
                va[l].x = (gk + 0 < D0) ? ap[gk + 0] : 0.f;
                va[l].y = (gk + 1 < D0) ? ap[gk + 1] : 0.f;
                va[l].z = (gk + 2 < D0) ? ap[gk + 2] : 0.f;
                va[l].w = (gk + 3 < D0) ? ap[gk + 3] : 0.f;
                vw[l].x = (gk + 0 < D0) ? wp[gk + 0] : 0.f;
                vw[l].y = (gk + 1 < D0) ? wp[gk + 1] : 0.f;
                vw[l].z = (gk + 2 < D0) ? wp[gk + 2] : 0.f;
                vw[l].w = (gk + 3 < D0) ? wp[gk + 3] : 0.f;
            }
        }
#pragma unroll
        for (int l = 0; l < 8; ++l) {
            const int f = tid + l * 128;
            const int r = f >> 3;
            const int k = (f & 7) * 4;
            As[swz(k + 0, r)] = va[l].x; As[swz(k + 1, r)] = va[l].y;
            As[swz(k + 2, r)] = va[l].z; As[swz(k + 3, r)] = va[l].w;
            Ws[swz(k + 0, r)] = vw[l].x; Ws[swz(k + 1, r)] = vw[l].y;
            Ws[swz(k + 2, r)] = vw[l].z; Ws[swz(k + 3, r)] = vw[l].w;
        }
        __syncthreads();

        // 8 k-quads; kx constant per quad
#pragma unroll 2
        for (int kq = 0; kq < 8; ++kq) {
#pragma unroll
            for (int kk = 0; kk < 4; ++kk) {
                const int k  = kq * 4 + kk;
                const int kb = k * BM;
                float a[16], b[8];
                *(float4*)&a[0]  = *(const float4*)&As[kb + ((ca[0] ^ kq) << 2)];
                *(float4*)&a[4]  = *(const float4*)&As[kb + ((ca[1] ^ kq) << 2)];
                *(float4*)&a[8]  = *(const float4*)&As[kb + ((ca[2] ^ kq) << 2)];
                *(float4*)&a[12] = *(const float4*)&As[kb + ((ca[3] ^ kq) << 2)];
                *(float4*)&b[0]  = *(const float4*)&Ws[kb + ((cb0  ^ kq) << 2)];
                *(float4*)&b[4]  = *(const float4*)&Ws[kb + ((cb1  ^ kq) << 2)];
#pragma unroll
                for (int i = 0; i < 16; ++i)
#pragma unroll
                    for (int j = 0; j < 8; ++j)
                        acc[i][j] = fmaf(a[i], b[j], acc[i][j]);
            }
        }
        __syncthreads();
    }

#pragma unroll
    for (int i = 0; i < 16; ++i) {
        float* cp = C + (size_t)(row0 + ty * 16 + i) * D1 + col0 + tx * 8;
        float4 v0 = make_float4(acc[i][0], acc[i][1], acc[i][2], acc[i][3]);
        float4 v1 = make_float4(acc[i][4], acc[i][5], acc[i][6], acc[i][7]);
        *(float4*)(cp + 0) = v0;
        *(float4*)(cp + 4) = v1;
    }
}

// ---------------------------------------------------------------------------
// Scan 1: in-place over pre1 buffer [T, B*512]; each thread owns one neuron.
// ---------------------------------------------------------------------------
__global__ __launch_bounds__(256)
void scan1_kernel(float* __restrict__ buf) {
#pragma clang fp contract(off)
    const int idx = blockIdx.x * blockDim.x + threadIdx.x;  // 0 .. 262143
    const int stride = BATCH * D1;
    float syn = 0.f, mem = 0.f;
    float* p = buf + idx;
    for (int t = 0; t < T_STEPS; ++t) {
        const float pre = p[(size_t)t * stride];
        float a = kALPHA * syn;
        syn = a + pre;
        const float reset = (mem > kTHR) ? 1.f : 0.f;
        float bm = kBETA * mem;
        mem = (bm + syn) * (1.f - reset);
        p[(size_t)t * stride] = (mem > kTHR) ? 1.f : 0.f;
    }
}

// ---------------------------------------------------------------------------
// GEMM2: C[M,20] = S1[M,512] * W2[20,512]^T.  W2 staged in LDS (40 KB).
// 256 threads = 64 rows x 4 k-quarters; shuffle-reduce across the 4.
// ---------------------------------------------------------------------------
__global__ __launch_bounds__(256)
void gemm2_kernel(const float* __restrict__ S1, const float* __restrict__ W2,
                  float* __restrict__ C) {
    __shared__ float Wsh[D2 * D1];  // 10240 floats = 40 KB
    for (int i = threadIdx.x; i < (D2 * D1) / 4; i += 256)
        ((float4*)Wsh)[i] = ((const float4*)W2)[i];
    __syncthreads();

    const int r  = threadIdx.x >> 2;   // 0..63
    const int kq = threadIdx.x & 3;    // k quarter (128 each)
    const int m  = blockIdx.x * 64 + r;

    const float4* src = (const float4*)(S1 + (size_t)m * D1 + kq * 128);
    float acc[D2];
#pragma unroll
    for (int o = 0; o < D2; ++o) acc[o] = 0.f;

    for (int j = 0; j < 32; ++j) {
        const float4 v = src[j];
        const float* wbase = Wsh + kq * 128 + j * 4;
#pragma unroll
        for (int o = 0; o < D2; ++o) {
            const float4 w = *(const float4*)(wbase + o * D1);
            acc[o] += v.x * w.x + v.y * w.y + v.z * w.z + v.w * w.w;
        }
    }
    // reduce over the 4 k-quarters (consecutive lanes)
#pragma unroll
    for (int o = 0; o < D2; ++o) {
        acc[o] += __shfl_xor(acc[o], 1);
        acc[o] += __shfl_xor(acc[o], 2);
    }
    if (kq == 0) {
        float* cp = C + (size_t)m * D2;
#pragma unroll
        for (int o = 0; o < D2; o += 4)
            *(float4*)(cp + o) = make_float4(acc[o], acc[o + 1], acc[o + 2], acc[o + 3]);
    }
}

// ---------------------------------------------------------------------------
// Scan 2: in-place over pre2 [T, B*20]; also writes the duplicate s2 slot.
// ---------------------------------------------------------------------------
__global__ __launch_bounds__(256)
void scan2_kernel(float* __restrict__ buf, float* __restrict__ dup) {
#pragma clang fp contract(off)
    const int idx = blockIdx.x * blockDim.x + threadIdx.x;  // 0 .. 10239
    const int stride = BATCH * D2;
    float syn = 0.f, mem = 0.f;
    for (int t = 0; t < T_STEPS; ++t) {
        const size_t off = (size_t)t * stride + idx;
        const float pre = buf[off];
        float a = kALPHA * syn;
        syn = a + pre;
        const float reset = (mem > kTHR) ? 1.f : 0.f;
        float bm = kBETA * mem;
        mem = (bm + syn) * (1.f - reset);
        const float s = (mem > kTHR) ? 1.f : 0.f;
        buf[off] = s;
        dup[off] = s;
    }
}

// ---------------------------------------------------------------------------
extern "C" void kernel_launch(void* const* d_in, const int* in_sizes, int n_in,
                              void* d_out, int out_size, void* d_ws, size_t ws_size,
                              hipStream_t stream) {
    const float* x  = (const float*)d_in[0];   // [100, 512, 700]
    const float* W1 = (const float*)d_in[1];   // [512, 700]
    const float* W2 = (const float*)d_in[2];   // [20, 512]
    float* out = (float*)d_out;

    float* s2a = out + OFF_S2A;   // [T,B,20]  (pre2 then s2)
    float* s1  = out + OFF_S1;    // [T,B,512] (pre1 then s1)
    float* s2b = out + OFF_S2B;   // [T,B,20]  duplicate s2

    // 1) pre1 = x @ W1^T  -> s1 slot  (1-D grid, XCD-chunked swizzle inside)
    gemm1_kernel<<<(M_ROWS / BM) * (D1 / BN), 128, 0, stream>>>(x, W1, s1);

    // 2) scan layer 1 in place (pre1 -> spikes)
    scan1_kernel<<<(BATCH * D1) / 256, 256, 0, stream>>>(s1);

    // 3) pre2 = s1 @ W2^T -> s2a slot
    gemm2_kernel<<<M_ROWS / 64, 256, 0, stream>>>(s1, W2, s2a);

    // 4) scan layer 2 in place + duplicate
    scan2_kernel<<<(BATCH * D2) / 256, 256, 0, stream>>>(s2a, s2b);
}